// Round 19
// baseline (65.675 us; speedup 1.0000x reference)
//
#include <hip/hip_runtime.h>

#define BB 8
#define NN 2048
#define HH 4
#define EE 64
#define MAXJ 128
#define NEG 0.2f
#define NCHUNK 32   // i-chunks for the se reduction

static constexpr int OFF_WGWST = 8;                          // [4][64] (written by k_se blk0)
static constexpr int OFF_S     = 264;                        // [8]
static constexpr int OFF_SWS   = 288;                        // float[N*E]
static constexpr int OFF_SATT  = OFF_SWS + NN * EE;          // float[B*H*N]
static constexpr int OFF_PART  = OFF_SATT + BB * HH * NN;    // float[NCHUNK*B*E]

// ---- fused per-row: 4-wave adj scan + SWS row + c_src/c_tgt + sparse softmax ----
__global__ __launch_bounds__(256) void k_fsatt(const int* __restrict__ adj,
                                               const float* __restrict__ state,
                                               const float* __restrict__ strucEmb,
                                               const float* __restrict__ Ws,
                                               const float* __restrict__ W_gat,
                                               const float* __restrict__ att,
                                               float* __restrict__ ws) {
    __shared__ int   s_jq[4][MAXJ];
    __shared__ int   s_c[4];
    __shared__ int   s_jl[MAXJ];
    __shared__ int   s_cnt;
    __shared__ float s_y[BB * MAXJ];
    __shared__ float s_cs[HH], s_ct[HH];
    const int i = blockIdx.x;
    const int t = threadIdx.x;
    const int w = t >> 6, lane = t & 63;

    // phase 1: each wave scans one quarter of adj row i (adj int32, verified r11/r13)
    {
        const int* a = adj + (size_t)i * NN + w * (NN / 4);
        int lc = 0;
        for (int it = 0; it < NN / 256; ++it) {
            int j = it * 64 + lane;
            bool edge = (a[j] == 0);
            unsigned long long m = __ballot(edge);
            if (edge) {
                int pos = lc + __popcll(m & ((1ull << lane) - 1ull));
                if (pos < MAXJ) s_jq[w][pos] = w * (NN / 4) + j;
            }
            lc += __popcll(m);
        }
        if (lane == 0) s_c[w] = lc > MAXJ ? MAXJ : lc;
    }
    __syncthreads();
    // deterministic merge (quarters in ascending j order)
    {
        int base = 0;
        for (int q = 0; q < w; ++q) base += s_c[q];
        int cw = s_c[w];
        for (int k = lane; k < cw; k += 64) {
            int pos = base + k;
            if (pos < MAXJ) s_jl[pos] = s_jq[w][k];
        }
        if (t == 0) {
            int tot = s_c[0] + s_c[1] + s_c[2] + s_c[3];
            s_cnt = tot > MAXJ ? MAXJ : tot;
        }
    }
    __syncthreads();
    const int cnt = s_cnt;

    if (w == 0) {
        // c_src/c_tgt (lanes 0..7), then SWS row (all 64 lanes)
        if (lane < 2 * HH) {
            int h = lane & 3;
            const float* wgh = W_gat + h * EE;
            const float* av  = att + h * 2 * EE + (lane >= HH ? EE : 0);
            float acc = 0.f;
            for (int e = 0; e < EE; ++e) acc += wgh[e] * av[e];
            if (lane < HH) s_cs[h] = acc; else s_ct[h] = acc;
        }
        float v = strucEmb[(size_t)i * EE + lane];
        float acc = 0.f;
        for (int e = 0; e < EE; ++e) acc += __shfl(v, e) * Ws[lane * EE + e];
        ws[OFF_SWS + i * EE + lane] = acc;
    } else {
        // waves 1-3: stage neighbor state values for all 8 batches
        for (int x = t - 64; x < BB * MAXJ; x += 192) {
            int k = x & (MAXJ - 1);
            if (k < cnt) s_y[x] = state[(x >> 7) * NN + s_jl[k]];
        }
    }
    __syncthreads();

    // 32 groups x 8 lanes: group = (b,h)
    int g = t >> 3, k0 = t & 7, b = g >> 2, h = g & 3;
    const float* yb = s_y + b * MAXJ;
    float ct = s_ct[h];
    float si = state[b * NN + i] * s_cs[h];
    float mmax = -1e30f;
    for (int k = k0; k < cnt; k += 8) {
        float e = si + ct * yb[k]; e = e > 0.f ? e : NEG * e;
        mmax = fmaxf(mmax, e);
    }
    for (int o = 4; o; o >>= 1) mmax = fmaxf(mmax, __shfl_xor(mmax, o, 8));
    float den = 0.f, num = 0.f;
    for (int k = k0; k < cnt; k += 8) {
        float y = yb[k];
        float e = si + ct * y; e = e > 0.f ? e : NEG * e;
        float p = expf(e - mmax);
        den += p; num += p * y;
    }
    for (int o = 4; o; o >>= 1) { den += __shfl_xor(den, o, 8); num += __shfl_xor(num, o, 8); }
    if (k0 == 0) ws[OFF_SATT + (b * HH + h) * NN + i] = num / den;
}

// ---- se partials (WgWst inline; block 0 publishes it for v13_out) ----
__global__ __launch_bounds__(256) void k_se(const float* __restrict__ W_gat,
                                            const float* __restrict__ Wst,
                                            float* __restrict__ ws) {
    int b = blockIdx.x & 7, chunk = blockIdx.x >> 3;
    int t = threadIdx.x; // 256
    int f = t & 63, sl = t >> 6;
    __shared__ float s_wg[HH * EE];
    s_wg[t] = W_gat[t];
    __syncthreads();
    float wgw[HH];
    {
        const float* wstf = Wst + f * EE;
        for (int h = 0; h < HH; ++h) {
            float acc = 0.f;
            for (int e = 0; e < EE; ++e) acc += s_wg[h * EE + e] * wstf[e];
            wgw[h] = acc;
        }
    }
    if (blockIdx.x == 0 && sl == 0)
        for (int h = 0; h < HH; ++h) ws[OFF_WGWST + h * EE + f] = wgw[h];
    float acc = 0.f;
    int i0 = chunk * (NN / NCHUNK);
    for (int i = i0 + sl; i < i0 + NN / NCHUNK; i += 4) {
        float v = ws[OFF_SWS + i * EE + f];
        for (int h = 0; h < HH; ++h)
            v += 0.25f * ws[OFF_SATT + (b * HH + h) * NN + i] * wgw[h];
        acc += fmaxf(v, 0.f);
    }
    __shared__ float red[256];
    red[t] = acc;
    __syncthreads();
    if (t < EE)
        ws[OFF_PART + (size_t)blockIdx.x * EE + t] =
            red[t] + red[t + 64] + red[t + 128] + red[t + 192];
}

// ---- S[b] = relu(se @ l1w.T + l1b) . l3w[:64] + l3b ----
__global__ void k_S(const float* __restrict__ lin1_w, const float* __restrict__ lin1_b,
                    const float* __restrict__ lin3_w, const float* __restrict__ lin3_b,
                    float* __restrict__ ws) {
    int b = blockIdx.x;
    int t = threadIdx.x; // 64
    __shared__ float s_se[EE];
    float se = 0.f;
    for (int c = 0; c < NCHUNK; ++c)
        se += ws[OFF_PART + (size_t)(c * BB + b) * EE + t];
    s_se[t] = se;
    __syncthreads();
    float bs = lin1_b[t];
    for (int f2 = 0; f2 < EE; ++f2) bs += s_se[f2] * lin1_w[t * EE + f2];
    float r = fmaxf(bs, 0.f) * lin3_w[t];
    for (int o = 32; o; o >>= 1) r += __shfl_xor(r, o);
    if (t == 0) ws[OFF_S + b] = r + lin3_b[0];
}

// ---- out[b,i] = S[b] + sum_f relu(beta_action)[f] * l3w[64+f] (f32 out) ----
__global__ void v13_out(const float* __restrict__ lin2_w, const float* __restrict__ lin2_b,
                        const float* __restrict__ lin3_w, const float* __restrict__ ws,
                        float* __restrict__ out) {
    int wave = blockIdx.x * 4 + (threadIdx.x >> 6);
    int lane = threadIdx.x & 63;
    int i = wave >> 3, b = wave & 7;
    float xv = ws[OFF_SWS + i * EE + lane];
    for (int h = 0; h < HH; ++h)
        xv += 0.25f * ws[OFF_SATT + (b * HH + h) * NN + i] * ws[OFF_WGWST + h * EE + lane];
    xv = fmaxf(xv, 0.f);
    float acc = lin2_b[lane];
    for (int f = 0; f < EE; ++f) acc += __shfl(xv, f) * lin2_w[lane * EE + f];
    float r = fmaxf(acc, 0.f) * lin3_w[EE + lane];
    for (int o = 32; o; o >>= 1) r += __shfl_xor(r, o);
    if (lane == 0) out[(size_t)b * NN + i] = ws[OFF_S + b] + r;
}

extern "C" void kernel_launch(void* const* d_in, const int* in_sizes, int n_in,
                              void* d_out, int out_size, void* d_ws, size_t ws_size,
                              hipStream_t stream) {
    const float* state    = (const float*)d_in[0];
    const float* strucEmb = (const float*)d_in[1];
    const int*   adj      = (const int*)d_in[2];   // int32 {0,1}, verified r11/r13
    const float* W_gat    = (const float*)d_in[3];
    const float* att      = (const float*)d_in[4];
    const float* Ws       = (const float*)d_in[5];
    const float* Wst      = (const float*)d_in[6];
    const float* lin1_w   = (const float*)d_in[7];
    const float* lin1_b   = (const float*)d_in[8];
    const float* lin2_w   = (const float*)d_in[9];
    const float* lin2_b   = (const float*)d_in[10];
    const float* lin3_w   = (const float*)d_in[11];
    const float* lin3_b   = (const float*)d_in[12];
    float* ws = (float*)d_ws;
    float* out = (float*)d_out;   // reference output dtype = float32 (verified r13)

    k_fsatt<<<dim3(NN),          dim3(256), 0, stream>>>(adj, state, strucEmb, Ws, W_gat, att, ws);
    k_se   <<<dim3(NCHUNK * BB), dim3(256), 0, stream>>>(W_gat, Wst, ws);
    k_S    <<<dim3(BB),          dim3(64),  0, stream>>>(lin1_w, lin1_b, lin3_w, lin3_b, ws);
    v13_out<<<dim3(NN * BB / 4), dim3(256), 0, stream>>>(lin2_w, lin2_b, lin3_w, ws, out);
}